// Round 10
// baseline (159.908 us; speedup 1.0000x reference)
//
#include <hip/hip_runtime.h>
#include <hip/hip_bf16.h>

#define BS  4
#define SEQ 4096
#define DK  128

// p = exp(s_raw / sqrt(128)) = exp2(C1_SCALE * s_raw).  C1_SCALE is folded
// into the bf16 cast of Q (replaces the cast rounding, does not add one), so
// the MFMA output is already in log2 domain: p = exp2(s).
#define C1_SCALE (1.4426950408889634f / 11.313708498984761f)

typedef __attribute__((ext_vector_type(8))) short bf16x8;
typedef __attribute__((ext_vector_type(4))) float f32x4;
typedef unsigned short ushort_t;

__device__ inline unsigned pk_bf16(float a, float b) {
    __hip_bfloat162 h = __float22bfloat162_rn(make_float2(a, b));
    union { __hip_bfloat162 h2; unsigned u; } cv;
    cv.h2 = h;
    return cv.u;
}

__device__ inline bf16x8 pk8(float4 a, float4 b) {
    union { bf16x8 v; unsigned u[4]; } r;
    r.u[0] = pk_bf16(a.x, a.y);
    r.u[1] = pk_bf16(a.z, a.w);
    r.u[2] = pk_bf16(b.x, b.y);
    r.u[3] = pk_bf16(b.z, b.w);
    return r.v;
}

// async global->LDS, 16B per lane; lds base must be wave-uniform
__device__ inline void gld_lds16(const ushort_t* g, ushort_t* l) {
    __builtin_amdgcn_global_load_lds(
        (const __attribute__((address_space(1))) unsigned int*)g,
        (__attribute__((address_space(3))) unsigned int*)l,
        16, 0, 0);
}

__device__ inline void bar_fence() {
    __builtin_amdgcn_s_barrier();
    asm volatile("" ::: "memory");
}

// ---------------------------------------------------------------------------
// Swizzled-row bf16 cast of Q (x C1_SCALE) and K: row r (256 B = 16 atoms of
// 16 B), atom a stored at position a ^ (r & 15).  Linear DMA of 16-row-aligned
// tiles reproduces the swizzled LDS image; fragment reads use atom
// ((c*4+quad) ^ ln) -> bank-balanced LDS reads.
// ---------------------------------------------------------------------------
__global__ __launch_bounds__(256) void cast_qk_sw(
    const float* __restrict__ Q, const float* __restrict__ K,
    ushort_t* __restrict__ Qb, ushort_t* __restrict__ Kb)
{
    const int g = blockIdx.x * 256 + threadIdx.x;   // atom id
    const int q = g >> 4, ap = g & 15;
    const int a = ap ^ (q & 15);
    const float* src = Q + (size_t)q * DK + a * 8;
    float4 x = *(const float4*)src, y = *(const float4*)(src + 4);
    x.x *= C1_SCALE; x.y *= C1_SCALE; x.z *= C1_SCALE; x.w *= C1_SCALE;
    y.x *= C1_SCALE; y.y *= C1_SCALE; y.z *= C1_SCALE; y.w *= C1_SCALE;
    *(bf16x8*)(Qb + (size_t)g * 8) = pk8(x, y);
    src = K + (size_t)q * DK + a * 8;
    float4 x2 = *(const float4*)src, y2 = *(const float4*)(src + 4);
    *(bf16x8*)(Kb + (size_t)g * 8) = pk8(x2, y2);
}

// ---------------------------------------------------------------------------
// Pass A: P tiles (bf16, numerator exp2(s)) + l[b,k] column-sum partials.
// Triple-buffered Qs DMA, ONE barrier/tile, counted FIFO-exact vmcnt (incl.
// the P stores); direct swizzled uint2 stores of P to Pg in the pv LDS
// image (Pg[b*64+qtile][ktile]: 64 q x 64 k, atom aa stored at aa^(ql&7)).
// grid (kt=32, qs=8, b=4) = 1024 blocks, 256 thr, 12 KB LDS.
// ---------------------------------------------------------------------------
__global__ __launch_bounds__(256) void sdpa_passA(
    const ushort_t* __restrict__ Qb, const ushort_t* __restrict__ Kb,
    ushort_t* __restrict__ Pg, float* __restrict__ lp)
{
    __shared__ ushort_t Qs[3][4096];   // 3 x (32 q x 128 dk), swizzled rows

    const int kt = blockIdx.x, qs = blockIdx.y, b = blockIdx.z;
    const int tid = threadIdx.x;
    const int w = tid >> 6, lane = tid & 63, ln = lane & 15, quad = lane >> 4;

    bf16x8 ka[2][4];   // A-frags: k rows kt*128 + w*32 + mt*16 + ln (swizzled)
#pragma unroll
    for (int mt = 0; mt < 2; ++mt)
#pragma unroll
        for (int c = 0; c < 4; ++c)
            ka[mt][c] = *(const bf16x8*)(Kb +
                ((size_t)(b * SEQ) + kt * 128 + w * 32 + mt * 16 + ln) * DK +
                (((c * 4 + quad) ^ ln) * 8));

    float ls[2][4] = {};
    const ushort_t* qtb = Qb + ((size_t)(b * SEQ + qs * 512)) * DK;
    // this wave's P k-tile: ktile = kt*2 + (w>>1); qtile base qs*8
    ushort_t* pgw = Pg + (((size_t)(b * 64 + qs * 8)) * 64 + kt * 2 + (w >> 1)) * 4096;

#define A_DMA(BUF, I)                                                          \
    {                                                                          \
        _Pragma("unroll")                                                      \
        for (int j = 0; j < 2; ++j)                                            \
            gld_lds16(qtb + (size_t)(I) * 4096 + (j * 256 + tid) * 8,          \
                      &Qs[BUF][(j * 256 + w * 64) * 8]);                       \
    }

#define A_CMP(BUF, T)                                                          \
    {                                                                          \
        bf16x8 qf[2][4];                                                       \
        _Pragma("unroll")                                                      \
        for (int nt = 0; nt < 2; ++nt)                                         \
            _Pragma("unroll")                                                  \
            for (int c = 0; c < 4; ++c)                                        \
                qf[nt][c] = *(const bf16x8*)&Qs[BUF][(nt * 16 + ln) * 128 +    \
                                    (((c * 4 + quad) ^ ln) * 8)];              \
        ushort_t* pgt = pgw + (size_t)((T) >> 1) * (64 * 4096);                \
        _Pragma("unroll")                                                      \
        for (int mt = 0; mt < 2; ++mt)                                         \
            _Pragma("unroll")                                                  \
            for (int nt = 0; nt < 2; ++nt) {                                   \
                f32x4 s = {0.f, 0.f, 0.f, 0.f};                                \
                __builtin_amdgcn_s_setprio(1);                                 \
                _Pragma("unroll")                                              \
                for (int c = 0; c < 4; ++c)                                    \
                    s = __builtin_amdgcn_mfma_f32_16x16x32_bf16(               \
                        ka[mt][c], qf[nt][c], s, 0, 0, 0);                     \
                __builtin_amdgcn_s_setprio(0);                                 \
                float e0 = __builtin_amdgcn_exp2f(s[0]);                       \
                float e1 = __builtin_amdgcn_exp2f(s[1]);                       \
                float e2 = __builtin_amdgcn_exp2f(s[2]);                       \
                float e3 = __builtin_amdgcn_exp2f(s[3]);                       \
                ls[mt][0] += e0; ls[mt][1] += e1;                              \
                ls[mt][2] += e2; ls[mt][3] += e3;                              \
                uint2 pw; pw.x = pk_bf16(e0, e1); pw.y = pk_bf16(e2, e3);      \
                const int ql = (((T) & 1) * 32) + nt * 16 + ln;                \
                const int aa = (w & 1) * 4 + mt * 2 + (quad >> 1);             \
                *(uint2*)&pgt[(ql * 8 + (aa ^ (ql & 7))) * 8 + (quad & 1) * 4] = pw; \
            }                                                                  \
    }

    A_DMA(0, 0)
    A_DMA(1, 1)
    for (int t = 0; t < 16; ++t) {
        // FIFO-exact wait for DMA(t): items issued after it =
        //  t==0: DMA(1)=2 | t==1: DMA(2)+stores(0)=6 | steady: 10 | t==15: 8
        if (t == 0)      asm volatile("s_waitcnt vmcnt(2)"  ::: "memory");
        else if (t == 1) asm volatile("s_waitcnt vmcnt(6)"  ::: "memory");
        else if (t < 15) asm volatile("s_waitcnt vmcnt(10)" ::: "memory");
        else             asm volatile("s_waitcnt vmcnt(8)"  ::: "memory");
        bar_fence();
        if (t < 14) A_DMA((t + 2) % 3, t + 2)
        A_CMP(t % 3, t)
    }
#undef A_DMA
#undef A_CMP

#pragma unroll
    for (int mt = 0; mt < 2; ++mt)
#pragma unroll
        for (int r = 0; r < 4; ++r) {
            float vv = ls[mt][r];
            vv += __shfl_xor(vv, 1);
            vv += __shfl_xor(vv, 2);
            vv += __shfl_xor(vv, 4);
            vv += __shfl_xor(vv, 8);
            ls[mt][r] = vv;
        }
    if (ln < 8) {
        int k = kt * 128 + w * 32 + (ln >> 2) * 16 + quad * 4 + (ln & 3);
        lp[((size_t)(qs * BS + b)) * SEQ + k] = ls[ln >> 2][ln & 3];
    }
}

// ---------------------------------------------------------------------------
// VbT[b][d][k] = bf16( V[b][k][d] / l[b][k] ), l = sum of 8 qs-partials.
// ---------------------------------------------------------------------------
__global__ __launch_bounds__(256) void vb_transpose(
    const float* __restrict__ V, const float* __restrict__ lp,
    ushort_t* __restrict__ VbT)
{
    __shared__ float Vl[64][132];
    __shared__ float Wl[64];

    const int kt = blockIdx.x, b = blockIdx.y;
    const int tid = threadIdx.x;
    const int k0 = kt * 64;
    {
        int r = tid >> 2, sg = tid & 3;
        const float* src = V + ((size_t)(b * SEQ) + k0 + r) * DK + sg * 32;
#pragma unroll
        for (int i = 0; i < 8; ++i)
            *(float4*)&Vl[r][sg * 32 + i * 4] = *(const float4*)(src + i * 4);
    }
    if (tid < 64) {
        float s = 0.f;
#pragma unroll
        for (int qs = 0; qs < 8; ++qs)
            s += lp[((size_t)(qs * BS + b)) * SEQ + k0 + tid];
        Wl[tid] = 1.0f / s;
    }
    __syncthreads();

    const int d = tid >> 1, kh = tid & 1;
    unsigned u[16];
#pragma unroll
    for (int j = 0; j < 16; ++j) {
        int row = kh * 32 + j * 2;
        u[j] = pk_bf16(Vl[row][d] * Wl[row], Vl[row + 1][d] * Wl[row + 1]);
    }
    ushort_t* dst = VbT + ((size_t)(b * DK) + d) * SEQ + k0 + kh * 32;
#pragma unroll
    for (int i = 0; i < 4; ++i) {
        uint4 t4; t4.x = u[i*4]; t4.y = u[i*4+1]; t4.z = u[i*4+2]; t4.w = u[i*4+3];
        *(uint4*)(dst + i * 8) = t4;
    }
}

// ---------------------------------------------------------------------------
// Pass B: O = P . V'  — WAVE-INDEPENDENT streaming PV GEMM, ZERO barriers in
// the main loop.  Block owns (32 q x 128 d); each wave owns a k-QUARTER
// (1024 k = 32 tiles of 32 k) and stages its own P (2 KB) + V (8 KB) 32-k
// sub-tiles into wave-private LDS (rows = 4 atoms of 16 B -> b128 reads hit
// the 8-lanes/bank-group floor with NO swizzle).  All hazards are intra-wave
// (counted vmcnt(10) depth-2 prefetch + own lgkmcnt).  Per-wave partial O
// (over its k-quarter) lives in 64 VGPRs; a single 2-barrier LDS reduction
// at the end sums the 4 waves (69.6 KB, reusing the 80 KB staging space).
// grid (x=128 qt32, y=4 b) = 512 blocks = 2 blocks/CU (160 KB LDS total).
// ---------------------------------------------------------------------------
__global__ __launch_bounds__(256) void sdpa_pv(
    const ushort_t* __restrict__ Pg, const ushort_t* __restrict__ VbT,
    float* __restrict__ O)
{
    // per buf / per wave: 1024 ushort P (32q x 32k) + 4096 ushort V (128d x 32k)
    __shared__ ushort_t S[2][4][5120];   // 80 KB

    const int qt32 = blockIdx.x, b = blockIdx.y;
    const int qt64 = qt32 >> 1, qh = qt32 & 1;
    const int tid = threadIdx.x;
    const int w = tid >> 6, lane = tid & 63, ln = lane & 15, quad = lane >> 4;
    const int lr = lane >> 2, lp = lane & 3;   // DMA coords: row-sub, atom-pos

    f32x4 acc[2][8];
#pragma unroll
    for (int i = 0; i < 2; ++i)
#pragma unroll
        for (int j = 0; j < 8; ++j) acc[i][j] = (f32x4){0.f, 0.f, 0.f, 0.f};

    // wave w's k-quarter: k = w*1024 + t*32, t = 0..31
    // P source tiles: [b*64+qt64][kt64 = w*16 + t/2], rows qh*32 + ql (64 ushort/row)
    const ushort_t* ptile0 = Pg + (((size_t)(b * 64 + qt64)) * 64 + w * 16) * 4096
                              + qh * 32 * 64;
    const ushort_t* vbase  = VbT + ((size_t)(b * DK)) * SEQ + w * 1024;

// stage one 32-k sub-tile into wave-private region (10 loads, all intra-wave):
// P: LDS slot (ql,p) holds global atom (4h+p) of row ql (un-permuting the
//    stored aa^(ql&7) image); V: rows contiguous 64 B.
#define PV_DMA(BUF, T)                                                         \
    {                                                                          \
        const ushort_t* pt = ptile0 + (size_t)((T) >> 1) * 4096;               \
        const int h4 = ((T) & 1) * 4;                                          \
        _Pragma("unroll")                                                      \
        for (int i = 0; i < 2; ++i) {                                          \
            const int ql = i * 16 + lr;                                        \
            gld_lds16(pt + ql * 64 + (((h4 + lp) ^ (ql & 7)) * 8),             \
                      &S[BUF][w][i * 512]);                                    \
        }                                                                      \
        _Pragma("unroll")                                                      \
        for (int j = 0; j < 8; ++j) {                                          \
            const int d = j * 16 + lr;                                         \
            gld_lds16(vbase + (size_t)d * SEQ + (T) * 32 + lp * 8,             \
                      &S[BUF][w][1024 + j * 512]);                             \
        }                                                                      \
    }

// one 32-k sub-tile: 2 P-frag reads + 8 V-frag reads + 16 MFMA.
// pa lane(ln,quad) = P[q=qf2*16+ln][k=quad*8..+7]; vf = V'[d=dt*16+ln][same k]
// (identical per-lane operand values to the round-9-verified math).
#define PV_CMP(BUF)                                                            \
    {                                                                          \
        bf16x8 pa[2];                                                          \
        _Pragma("unroll")                                                      \
        for (int qf2 = 0; qf2 < 2; ++qf2)                                      \
            pa[qf2] = *(const bf16x8*)&S[BUF][w][(qf2 * 16 + ln) * 32 + quad * 8]; \
        _Pragma("unroll")                                                      \
        for (int dt = 0; dt < 8; ++dt) {                                       \
            bf16x8 vf = *(const bf16x8*)&S[BUF][w][1024 + (dt * 16 + ln) * 32 + quad * 8]; \
            __builtin_amdgcn_s_setprio(1);                                     \
            acc[0][dt] = __builtin_amdgcn_mfma_f32_16x16x32_bf16(pa[0], vf, acc[0][dt], 0, 0, 0); \
            acc[1][dt] = __builtin_amdgcn_mfma_f32_16x16x32_bf16(pa[1], vf, acc[1][dt], 0, 0, 0); \
            __builtin_amdgcn_s_setprio(0);                                     \
        }                                                                      \
    }

    PV_DMA(0, 0)
    PV_DMA(1, 1)
    for (int t = 0; t < 32; ++t) {
        // per-wave FIFO: after prologue/steady issue, 20 loads outstanding;
        // vmcnt(10) = tile t fully landed, tile t+1's 10 stay in flight.
        if (t < 31) asm volatile("s_waitcnt vmcnt(10)" ::: "memory");
        else        asm volatile("s_waitcnt vmcnt(0)"  ::: "memory");
        PV_CMP(t & 1)
        asm volatile("s_waitcnt lgkmcnt(0)" ::: "memory");   // reads done before rewrite
        if (t < 30) PV_DMA(t & 1, t + 2)
    }
#undef PV_DMA
#undef PV_CMP

    // cross-wave reduction: O[q][d] = sum_w acc_w.  R = [4 waves][32 q][136]
    // floats (69.6 KB) overlaid on S.  acc[qf2][dt][r] -> q = qf2*16+quad*4+r,
    // d = dt*16+ln (round-9-verified C layout).
    float* R = (float*)&S[0][0][0];
    __syncthreads();                  // all waves done reading their buffers
#pragma unroll
    for (int qf2 = 0; qf2 < 2; ++qf2)
#pragma unroll
        for (int dt = 0; dt < 8; ++dt)
#pragma unroll
            for (int r = 0; r < 4; ++r)
                R[w * 4352 + (qf2 * 16 + quad * 4 + r) * 136 + dt * 16 + ln] =
                    acc[qf2][dt][r];
    __syncthreads();
    {
        const int q = tid >> 3, d0 = (tid & 7) * 16;
        float* dst = O + ((size_t)(b * SEQ) + qt32 * 32 + q) * DK + d0;
#pragma unroll
        for (int ii = 0; ii < 4; ++ii) {
            float4 s4; s4.x = s4.y = s4.z = s4.w = 0.f;
#pragma unroll
            for (int wv = 0; wv < 4; ++wv) {
                const float* r4 = &R[wv * 4352 + q * 136 + d0 + ii * 4];
                s4.x += r4[0]; s4.y += r4[1]; s4.z += r4[2]; s4.w += r4[3];
            }
            *(float4*)(dst + ii * 4) = s4;
        }
    }
}

extern "C" void kernel_launch(void* const* d_in, const int* in_sizes, int n_in,
                              void* d_out, int out_size, void* d_ws, size_t ws_size,
                              hipStream_t stream) {
    const float* q = (const float*)d_in[0];
    const float* k = (const float*)d_in[1];
    const float* v = (const float*)d_in[2];
    float* out = (float*)d_out;

    const size_t QKV = (size_t)BS * SEQ * DK;           // 2 M elements
    float*    lp  = (float*)d_ws;                       // 512 KB used
    ushort_t* Qb  = (ushort_t*)((char*)d_ws + (1 << 20));
    ushort_t* Kb  = Qb + QKV;
    ushort_t* VbT = Kb + QKV;
    ushort_t* Pg  = VbT + QKV;                          // 134 MB P tiles
    (void)ws_size;

    cast_qk_sw <<<dim3(BS * SEQ * 16 / 256), 256, 0, stream>>>(q, k, Qb, Kb);
    sdpa_passA <<<dim3(32, 8, 4), 256, 0, stream>>>(Qb, Kb, Pg, lp);
    vb_transpose<<<dim3(64, 4),   256, 0, stream>>>(v, lp, VbT);
    sdpa_pv    <<<dim3(128, 4),   256, 0, stream>>>(Pg, VbT, out);
}